// Round 5
// baseline (649.196 us; speedup 1.0000x reference)
//
#include <hip/hip_runtime.h>
#include <hip/hip_fp16.h>

// ---------------------------------------------------------------------------
// TNO-v2 forward. Round 10: big-GEMM pipeline deepened from 2 to 3 LDS
// buffers (depth-2 prefetch). Tile t's loads are issued two compute phases
// (~900cy) before their vmcnt drain -> HBM latency fully covered; vmcnt(6)
// keeps 2 tiles in flight, never draining to 0 in the loop. LDS 72KB ->
// still 2 blocks/CU. Buffer-reuse hazard distance identical to r9's proven
// double-buffer. dpb GEMMs (r6 2-phase) and conv/kfft unchanged.
// ---------------------------------------------------------------------------

#define FFTN 8192
#define SWZ(p) ((p) ^ (((p) >> 8) & 31))

#define C45F 0.70710678118654752f
#define CC8F 0.92387953251128676f   /* cos(pi/8) */
#define SS8F 0.38268343236508977f   /* sin(pi/8) */

typedef unsigned short u16;
typedef unsigned int u32;
typedef __attribute__((ext_vector_type(8))) short bf16x8;
typedef __attribute__((ext_vector_type(4))) float f32x4;

__device__ __forceinline__ int brev13(int x) { return (int)(__brev((unsigned)x) >> 19); }
__device__ __forceinline__ float b2f(u16 u) {
  union { float f; u32 i; } c; c.i = ((u32)u) << 16; return c.f;
}
__device__ __forceinline__ u16 f2b(float f) {
  union { float f; u32 i; } c; c.f = f;
  u32 r = c.i + 0x7FFFu + ((c.i >> 16) & 1u);
  return (u16)(r >> 16);
}
__device__ __forceinline__ float silu_f(float x) { return x / (1.f + __expf(-x)); }

// packed half2 <-> 2xfloat
__device__ __forceinline__ float2 up2(u32 v) {
  __half2 h = __builtin_bit_cast(__half2, v);
  return make_float2(__low2float(h), __high2float(h));
}
__device__ __forceinline__ u32 dn2(float r, float i) {
  __half2 h = __floats2half2_rn(r, i);
  return __builtin_bit_cast(u32, h);
}

// async global->LDS, 16B per lane; LDS dest must be wave-uniform base + lane*16
__device__ __forceinline__ void gload16(const void* g, void* l) {
  __builtin_amdgcn_global_load_lds(
      (const __attribute__((address_space(1))) u32*)g,
      (__attribute__((address_space(3))) u32*)l, 16, 0, 0);
}

// ---------------- twiddles ---------------------------------------------------
__global__ void twiddle_init_kernel(float2* __restrict__ tw) {
  int k = blockIdx.x * blockDim.x + threadIdx.x;
  if (k < 4096) {
    double ang = -6.283185307179586476925286766559 * ((double)k / 8192.0);
    tw[k] = make_float2((float)cos(ang), (float)sin(ang));
  }
}

// ---------------- SimpleRMSNorm (fp32 in -> bf16 out, optional relu) --------
__global__ __launch_bounds__(256) void srms_bf16_kernel(
    const float* __restrict__ in, u16* __restrict__ out, int rows, int do_relu)
{
  int wave = threadIdx.x >> 6, lane = threadIdx.x & 63;
  int row = (blockIdx.x << 2) + wave;
  if (row >= rows) return;
  const float4* p = (const float4*)(in + (size_t)row * 512);
  float4 a = p[lane], b = p[lane + 64];
  float ss = a.x*a.x + a.y*a.y + a.z*a.z + a.w*a.w
           + b.x*b.x + b.y*b.y + b.z*b.z + b.w*b.w;
#pragma unroll
  for (int off = 32; off > 0; off >>= 1) ss += __shfl_xor(ss, off);
  float inv = 1.0f / (sqrtf(ss) * 0.04419417382415922f + 1e-8f);
  a.x *= inv; a.y *= inv; a.z *= inv; a.w *= inv;
  b.x *= inv; b.y *= inv; b.z *= inv; b.w *= inv;
  if (do_relu) {
    a.x = fmaxf(a.x, 0.f); a.y = fmaxf(a.y, 0.f); a.z = fmaxf(a.z, 0.f); a.w = fmaxf(a.w, 0.f);
    b.x = fmaxf(b.x, 0.f); b.y = fmaxf(b.y, 0.f); b.z = fmaxf(b.z, 0.f); b.w = fmaxf(b.w, 0.f);
  }
  u16* o = out + (size_t)row * 512;
  ushort4 s0, s1;
  s0.x = f2b(a.x); s0.y = f2b(a.y); s0.z = f2b(a.z); s0.w = f2b(a.w);
  s1.x = f2b(b.x); s1.y = f2b(b.y); s1.z = f2b(b.z); s1.w = f2b(b.w);
  *(ushort4*)(o + lane * 4) = s0;
  *(ushort4*)(o + 256 + lane * 4) = s1;
}

// ---------------- DPB layer 0 (bf16 out) ------------------------------------
__global__ __launch_bounds__(256) void dpb0_kernel(
    const float* __restrict__ Wp, const float* __restrict__ bp, u16* __restrict__ out)
{
  int wave = threadIdx.x >> 6, lane = threadIdx.x & 63;
  int row = (blockIdx.x << 2) + wave;   // circulant index 0..8191
  if (row >= 8192) return;
  float pv;
  if (row == 0 || row == 4096) pv = 0.f;
  else if (row < 4096) pv = (float)row;
  else pv = (float)(row - 8192);
  const float4* wp  = (const float4*)Wp;
  const float4* bpp = (const float4*)bp;
  float4 a = wp[lane], b = wp[lane + 64];
  float4 c = bpp[lane], d = bpp[lane + 64];
  a.x = fmaf(pv, a.x, c.x); a.y = fmaf(pv, a.y, c.y);
  a.z = fmaf(pv, a.z, c.z); a.w = fmaf(pv, a.w, c.w);
  b.x = fmaf(pv, b.x, d.x); b.y = fmaf(pv, b.y, d.y);
  b.z = fmaf(pv, b.z, d.z); b.w = fmaf(pv, b.w, d.w);
  float ss = a.x*a.x + a.y*a.y + a.z*a.z + a.w*a.w
           + b.x*b.x + b.y*b.y + b.z*b.z + b.w*b.w;
#pragma unroll
  for (int off = 32; off > 0; off >>= 1) ss += __shfl_xor(ss, off);
  float inv = 1.0f / (sqrtf(ss) * 0.04419417382415922f + 1e-8f);
  u16* o = out + (size_t)row * 512;
  ushort4 s0, s1;
  s0.x = f2b(fmaxf(a.x * inv, 0.f)); s0.y = f2b(fmaxf(a.y * inv, 0.f));
  s0.z = f2b(fmaxf(a.z * inv, 0.f)); s0.w = f2b(fmaxf(a.w * inv, 0.f));
  s1.x = f2b(fmaxf(b.x * inv, 0.f)); s1.y = f2b(fmaxf(b.y * inv, 0.f));
  s1.z = f2b(fmaxf(b.z * inv, 0.f)); s1.w = f2b(fmaxf(b.w * inv, 0.f));
  *(ushort4*)(o + lane * 4) = s0;
  *(ushort4*)(o + 256 + lane * 4) = s1;
}

// ---------------- weight transpose+cast: fp32 (R,C) -> bf16 (C,R) -----------
__global__ __launch_bounds__(256) void wtrans_kernel(
    const float* __restrict__ in, u16* __restrict__ out, int R, int C)
{
  __shared__ float tile[32][33];
  const int c0 = blockIdx.x << 5, r0 = blockIdx.y << 5;
  const int tx = threadIdx.x, ty = threadIdx.y;
#pragma unroll
  for (int i = 0; i < 32; i += 8)
    tile[ty + i][tx] = in[(size_t)(r0 + ty + i) * C + c0 + tx];
  __syncthreads();
#pragma unroll
  for (int i = 0; i < 32; i += 8)
    out[(size_t)(c0 + ty + i) * R + r0 + tx] = f2b(tile[tx][ty + i]);
}

// ---------------- bf16 transpose: (8, 512, 4096) -> (8, 4096, 512) ----------
__global__ __launch_bounds__(256) void transpose_b16_kernel(
    const u16* __restrict__ in, u16* __restrict__ out)
{
  __shared__ u16 tile[32][33];
  const int b = blockIdx.z;
  const int j0 = blockIdx.x << 5, c0 = blockIdx.y << 5;
  const int tx = threadIdx.x, ty = threadIdx.y;
  const u16* ip = in + ((size_t)b << 21);
  u16* op = out + ((size_t)b << 21);
#pragma unroll
  for (int i = 0; i < 32; i += 8)
    tile[ty + i][tx] = ip[(size_t)(c0 + ty + i) * 4096 + j0 + tx];
  __syncthreads();
#pragma unroll
  for (int i = 0; i < 32; i += 8)
    op[(size_t)(j0 + ty + i) * 512 + c0 + tx] = tile[tx][ty + i];
}

// ---------------- MFMA bf16 GEMM (r6 2-phase, 128x128 tile) -----------------
// Used for the small dpb GEMMs only.  EPI: 0 plain fp32 | 5 fp32 C^T
template <int EPI>
__global__ __launch_bounds__(256) void gemm_bf16_kernel(
    const u16* __restrict__ A, const u16* __restrict__ Bt,
    const float* __restrict__ bias, const u16* __restrict__ aux16,
    const float* __restrict__ auxf, void* __restrict__ Cv,
    int M, int N, int K)
{
  __shared__ __align__(16) u16 As[4096];   // [khalf(4)][m(128)][8 bf16]
  __shared__ __align__(16) u16 Bs[4096];   // [khalf(4)][n(128)][8 bf16]
  const int tid = threadIdx.x;
  const int lane = tid & 63;
  const int w = tid >> 6;
  const int wm = (w >> 1) << 6;
  const int wn = (w & 1) << 6;
  const int lm = lane & 15;
  const int lq = lane >> 4;
  const int bm = blockIdx.y << 7;
  const int bn = blockIdx.x << 7;

  const int sm = tid & 127;     // staging row within tile
  const int sk = tid >> 7;      // 0/1 -> khalf sk (phase 0) and 2+sk (phase 1)
  const u16* Ap = A + (size_t)(bm + sm) * K + sk * 8;
  const u16* Bp = Bt + (size_t)(bn + sm) * K + sk * 8;
  u16* As0 = As + ((sk)     * 128 + sm) * 8;
  u16* As1 = As + ((2 + sk) * 128 + sm) * 8;
  u16* Bs0 = Bs + ((sk)     * 128 + sm) * 8;
  u16* Bs1 = Bs + ((2 + sk) * 128 + sm) * 8;

  f32x4 acc[4][4];
#pragma unroll
  for (int i = 0; i < 4; i++)
#pragma unroll
    for (int j = 0; j < 4; j++) acc[i][j] = (f32x4){0.f, 0.f, 0.f, 0.f};

  for (int k0 = 0; k0 < K; k0 += 32) {
    __syncthreads();                       // prior tile fully consumed
    gload16(Ap, As0); gload16(Ap + 16, As1);
    gload16(Bp, Bs0); gload16(Bp + 16, Bs1);
    Ap += 32; Bp += 32;
    __builtin_amdgcn_s_waitcnt(0);         // drain global_load_lds
    __syncthreads();
    bf16x8 af[4], bfr[4];
#pragma unroll
    for (int i = 0; i < 4; i++) {
      af[i]  = *(const bf16x8*)(As + (lq * 128 + wm + i * 16 + lm) * 8);
      bfr[i] = *(const bf16x8*)(Bs + (lq * 128 + wn + i * 16 + lm) * 8);
    }
#pragma unroll
    for (int i = 0; i < 4; i++)
#pragma unroll
      for (int j = 0; j < 4; j++)
        acc[i][j] = __builtin_amdgcn_mfma_f32_16x16x32_bf16(af[i], bfr[j], acc[i][j], 0, 0, 0);
  }

  // epilogue: lane holds C[m0 + r][n] for r=0..3 per (i,j) tile
#pragma unroll
  for (int i = 0; i < 4; i++) {
    const int m0 = bm + wm + i * 16 + lq * 4;
#pragma unroll
    for (int j = 0; j < 4; j++) {
      const int n = bn + wn + j * 16 + lm;
      const float bb = bias[n];
      const f32x4 v = acc[i][j];
      if constexpr (EPI == 5) {
        // C^T[n][m] fp32, rows r consecutive in m
        float4 o = make_float4(v[0] + bb, v[1] + bb, v[2] + bb, v[3] + bb);
        *(float4*)((float*)Cv + (size_t)n * M + m0) = o;
      } else {
#pragma unroll
        for (int r = 0; r < 4; r++) {
          const size_t idx = (size_t)(m0 + r) * N + n;
          const float val = v[r] + bb;
          if constexpr (EPI == 0) ((float*)Cv)[idx] = val;
          if constexpr (EPI == 1) ((u16*)Cv)[idx] = f2b(silu_f(val));
          if constexpr (EPI == 3) ((u16*)Cv)[idx] = f2b(val * b2f(aux16[idx]));
          if constexpr (EPI == 4) ((float*)Cv)[idx] = val + auxf[idx];
        }
      }
    }
  }
}

// ---------------- MFMA bf16 GEMM, 128x256 tile, BK=32, triple-buffered ------
// EPI: 1 silu bf16 | 2 silu bf16 transposed (VT: b,c,j) | 3 gate | 4 +auxf fp32
// Requires M%128==0, N%256==0, K%32==0, K>=96.
// LDS: A [buf3][kq(4)][row(128)][8] 24KB, B [buf3][h(2)][kq(4)][row(128)][8]
// 48KB -> 72KB total -> 2 blocks/CU. acc[4][4]=64 VGPR, 8 waves (2M x 4N),
// launch_bounds(512,4) -> 4 waves/SIMD.
// Depth-2 prefetch: iteration t stages tile t+2 and waits vmcnt(6) -- tile
// t's 3 loads (issued two compute phases earlier, ~900cy) drain with zero
// stall; tiles t+1/t+2 (6 loads) stay in flight. Tail: vmcnt(3), vmcnt(0).
template <int EPI>
__global__ __launch_bounds__(512, 4) void gemm128x256_bf16_kernel(
    const u16* __restrict__ A, const u16* __restrict__ Bt,
    const float* __restrict__ bias, const u16* __restrict__ aux16,
    const float* __restrict__ auxf, void* __restrict__ Cv,
    int M, int N, int K)
{
  __shared__ __align__(16) u16 Asm[3][4096];   // 3 x 8 KB
  __shared__ __align__(16) u16 Bsm[3][8192];   // 3 x 16 KB
  const int tid = threadIdx.x;          // 0..511
  const int lane = tid & 63;
  const int w = tid >> 6;               // 0..7 waves (2M x 4N)
  const int wm = (w >> 2) << 6;         // 0,64
  const int wn = (w & 3) << 6;          // 0,64,128,192
  const int lm = lane & 15;
  const int lq = lane >> 4;             // 0..3
  const int bm = blockIdx.y << 7;
  const int bn = blockIdx.x << 8;

  // staging: thread -> (row = tid&127, kq = tid>>7); 16B per load
  const int rloc = tid & 127;
  const int kq = tid >> 7;              // 0..3
  const u16* Ag = A + (size_t)(bm + rloc) * K + kq * 8;
  const u16* Bg = Bt + (size_t)(bn + rloc) * K + kq * 8;
  const size_t bh = (size_t)128 * K;    // B half-tile row step (u16)
  const int lso = tid * 8;              // linear LDS dest (u16 units)

  f32x4 acc[4][4];
#pragma unroll
  for (int i = 0; i < 4; i++)
#pragma unroll
    for (int j = 0; j < 4; j++) acc[i][j] = (f32x4){0.f, 0.f, 0.f, 0.f};

#define STG3(buf, kt) do {                                            \
    const u16* a_ = Ag + (size_t)(kt) * 32;                           \
    const u16* b_ = Bg + (size_t)(kt) * 32;                           \
    gload16(a_, &Asm[buf][0] + lso);                                  \
    gload16(b_, &Bsm[buf][0] + lso);                                  \
    gload16(b_ + bh, &Bsm[buf][0] + 4096 + lso);                      \
  } while (0)

  // prologue: tiles 0,1 -> buffers 0,1
  STG3(0, 0);
  STG3(1, 1);

  const int NT = K >> 5;
  int cb = 0;
  for (int t = 0; t < NT; ++t) {
    const u16* cA = &Asm[cb][0];
    const u16* cB = &Bsm[cb][0];
    if (t + 2 < NT) {
      int nb2 = cb + 2; if (nb2 >= 3) nb2 -= 3;
      STG3(nb2, t + 2);
      asm volatile("s_waitcnt vmcnt(6)" ::: "memory");  // tile t landed; t+1,t+2 in flight
    } else if (t + 1 < NT) {
      asm volatile("s_waitcnt vmcnt(3)" ::: "memory");
    } else {
      asm volatile("s_waitcnt vmcnt(0)" ::: "memory");
    }
    __builtin_amdgcn_sched_barrier(0);
    __builtin_amdgcn_s_barrier();
    bf16x8 bfr[4];
#pragma unroll
    for (int j = 0; j < 4; ++j) {
      const int c = wn + j * 16 + lm;                    // 0..255
      bfr[j] = *(const bf16x8*)(cB + (c >> 7) * 4096 + lq * 1024 + (c & 127) * 8);
    }
#pragma unroll
    for (int qm = 0; qm < 2; ++qm) {
      bf16x8 af[2];
#pragma unroll
      for (int i2 = 0; i2 < 2; ++i2)
        af[i2] = *(const bf16x8*)(cA + lq * 1024 + (wm + qm * 32 + i2 * 16 + lm) * 8);
      __builtin_amdgcn_s_setprio(1);
#pragma unroll
      for (int i2 = 0; i2 < 2; ++i2)
#pragma unroll
        for (int j = 0; j < 4; ++j)
          acc[qm * 2 + i2][j] = __builtin_amdgcn_mfma_f32_16x16x32_bf16(
              af[i2], bfr[j], acc[qm * 2 + i2][j], 0, 0, 0);
      __builtin_amdgcn_s_setprio(0);
    }
    __builtin_amdgcn_s_barrier();
    cb += 1; if (cb >= 3) cb -= 3;
  }
#undef STG3

  // epilogue
#pragma unroll
  for (int i = 0; i < 4; i++) {
    const int m0 = bm + wm + i * 16 + lq * 4;
#pragma unroll
    for (int j = 0; j < 4; j++) {
      const int n = bn + wn + j * 16 + lm;
      const float bb = bias[n];
      const f32x4 v = acc[i][j];
      if constexpr (EPI == 2) {
        const int b = m0 >> 12;
        const int jq = m0 & 4095;
        ushort4 s;
        s.x = f2b(silu_f(v[0] + bb)); s.y = f2b(silu_f(v[1] + bb));
        s.z = f2b(silu_f(v[2] + bb)); s.w = f2b(silu_f(v[3] + bb));
        *(ushort4*)((u16*)Cv + (((size_t)(b * 512 + n)) << 12) + jq) = s;
      } else {
#pragma unroll
        for (int r = 0; r < 4; r++) {
          const size_t idx = (size_t)(m0 + r) * N + n;
          const float val = v[r] + bb;
          if constexpr (EPI == 1) ((u16*)Cv)[idx] = f2b(silu_f(val));
          if constexpr (EPI == 3) ((u16*)Cv)[idx] = f2b(val * b2f(aux16[idx]));
          if constexpr (EPI == 4) ((float*)Cv)[idx] = val + auxf[idx];
        }
      }
    }
  }
}

// ============================================================================
// fp32 FFT core (kfft only)
// ============================================================================
__device__ __forceinline__ void fft8192_dit(float* sr, float* si,
                                            const float2* __restrict__ tw)
{
  const int t = threadIdx.x;
  for (int s = 0; s < 12; s += 2) {
    __syncthreads();
    const int h = 1 << s;
#pragma unroll
    for (int bb = 0; bb < 4; bb++) {
      const int u = t + (bb << 9);
      const int j = u & (h - 1);
      const int base = ((u >> s) << (s + 2)) | j;
      const float2 w1 = tw[j << (12 - s)];
      const float2 w2 = tw[j << (11 - s)];
      const int q0 = SWZ(base), q1 = SWZ(base + h);
      const int q2 = SWZ(base + 2 * h), q3 = SWZ(base + 3 * h);
      const float ar = sr[q0], ai = si[q0];
      const float br = sr[q1], bi = si[q1];
      const float cr = sr[q2], ci = si[q2];
      const float dr = sr[q3], di = si[q3];
      const float t1r = br * w1.x - bi * w1.y, t1i = br * w1.y + bi * w1.x;
      const float t2r = dr * w1.x - di * w1.y, t2i = dr * w1.y + di * w1.x;
      const float Ar = ar + t1r, Ai = ai + t1i;
      const float Br = ar - t1r, Bi = ai - t1i;
      const float Cr = cr + t2r, Ci = ci + t2i;
      const float Dr = cr - t2r, Di = ci - t2i;
      const float t3r = Cr * w2.x - Ci * w2.y, t3i = Cr * w2.y + Ci * w2.x;
      const float pr  = Dr * w2.x - Di * w2.y, pi  = Dr * w2.y + Di * w2.x;
      const float t4r = pi, t4i = -pr;
      sr[q0] = Ar + t3r; si[q0] = Ai + t3i;
      sr[q2] = Ar - t3r; si[q2] = Ai - t3i;
      sr[q1] = Br + t4r; si[q1] = Bi + t4i;
      sr[q3] = Br - t4r; si[q3] = Bi - t4i;
    }
  }
  __syncthreads();
#pragma unroll
  for (int bb = 0; bb < 8; bb++) {
    const int u = t + (bb << 9);
    const float2 w = tw[u];
    const int p0 = SWZ(u), p1 = SWZ(u + 4096);
    const float br = sr[p1], bi = si[p1];
    const float trr = br * w.x - bi * w.y;
    const float tri = br * w.y + bi * w.x;
    const float ar = sr[p0], ai = si[p0];
    sr[p0] = ar + trr; si[p0] = ai + tri;
    sr[p1] = ar - trr; si[p1] = ai - tri;
  }
  __syncthreads();
}

// ---------------- kernel spectra (fp32, reads transposed D1T coalesced) -----
__global__ __launch_bounds__(512) void kfft_kernel(
    const float* __restrict__ D1T,    // (512, 8192) fp32
    const float2* __restrict__ tw,
    float2* __restrict__ aspec)
{
  __shared__ float sr[FFTN];
  __shared__ float si[FFTN];
  const int q = blockIdx.x;
  const int t = threadIdx.x;
  const float* row0 = D1T + ((size_t)(2 * q)) * 8192;
  const float* row1 = row0 + 8192;
#pragma unroll
  for (int it = 0; it < 16; it++) {
    const int r = t + (it << 9);
    const int d = SWZ(brev13(r));
    sr[d] = row0[r]; si[d] = row1[r];
  }
  fft8192_dit(sr, si, tw);
  // fold inverse-FFT 1/8192 scale into the spectra
  const float sc = 1.0f / 8192.0f;
  float2* O0 = aspec + (size_t)(2 * q) * 4097;
  float2* O1 = aspec + (size_t)(2 * q + 1) * 4097;
#pragma unroll 1
  for (int it = 0; it < 8; it++) {
    const int k = t + (it << 9);
    const int k2 = (FFTN - k) & (FFTN - 1);
    const float zr = sr[SWZ(k)],  zi = si[SWZ(k)];
    const float wr = sr[SWZ(k2)], wi = si[SWZ(k2)];
    O0[k] = make_float2(0.5f * sc * (zr + wr), 0.5f * sc * (zi - wi));
    O1[k] = make_float2(0.5f * sc * (zi + wi), 0.5f * sc * (wr - zr));
  }
  if (t == 0) {
    const float zr = sr[SWZ(4096)], zi = si[SWZ(4096)];
    O0[4096] = make_float2(zr * sc, 0.f);
    O1[4096] = make_float2(zi * sc, 0.f);
  }
}

// ============================================================================
// conv: radix-16 register-butterfly FFT, half2 LDS storage (fp32 math)
// ============================================================================

// DIT radix-16 butterfly (levels of distance 1,2,4,8 within x[16]).
__device__ __forceinline__ void dit16(float* xr, float* xi,
    float wAr, float wAi, float wBr, float wBi,
    float wCr, float wCi, float wDr, float wDi)
{
#define DITP(a, b, wr_, wi_)                                     \
  { const float cr_ = xr[b]*(wr_) - xi[b]*(wi_);                 \
    const float ci_ = xr[b]*(wi_) + xi[b]*(wr_);                 \
    xr[b] = xr[a] - cr_; xi[b] = xi[a] - ci_;                    \
    xr[a] = xr[a] + cr_; xi[a] = xi[a] + ci_; }
#define DITPM(a, b, wr_, wi_)                                    \
  { const float cr_ = xr[b]*(wr_) - xi[b]*(wi_);                 \
    const float ci_ = xr[b]*(wi_) + xi[b]*(wr_);                 \
    xr[b] = xr[a] - ci_; xi[b] = xi[a] + cr_;                    \
    xr[a] = xr[a] + ci_; xi[a] = xi[a] - cr_; }
  // L1 (distance 1): all pairs share wA
  DITP(0,1,wAr,wAi)   DITP(2,3,wAr,wAi)   DITP(4,5,wAr,wAi)   DITP(6,7,wAr,wAi)
  DITP(8,9,wAr,wAi)   DITP(10,11,wAr,wAi) DITP(12,13,wAr,wAi) DITP(14,15,wAr,wAi)
  // L2 (distance 2): q=0 -> wB, q=1 -> wB*(-i)
  DITP(0,2,wBr,wBi)   DITPM(1,3,wBr,wBi)
  DITP(4,6,wBr,wBi)   DITPM(5,7,wBr,wBi)
  DITP(8,10,wBr,wBi)  DITPM(9,11,wBr,wBi)
  DITP(12,14,wBr,wBi) DITPM(13,15,wBr,wBi)
  // L3 (distance 4): q -> wC * e^{-i pi q/4}
  const float wC1r = C45F*(wCr + wCi), wC1i = C45F*(wCi - wCr);
  DITP(0,4,wCr,wCi)   DITP(1,5,wC1r,wC1i)   DITPM(2,6,wCr,wCi)   DITPM(3,7,wC1r,wC1i)
  DITP(8,12,wCr,wCi)  DITP(9,13,wC1r,wC1i)  DITPM(10,14,wCr,wCi) DITPM(11,15,wC1r,wC1i)
  // L4 (distance 8): q -> wD * e^{-i pi q/8}
  const float wD1r = wDr*CC8F + wDi*SS8F, wD1i = wDi*CC8F - wDr*SS8F;
  const float wD2r = C45F*(wDr + wDi),    wD2i = C45F*(wDi - wDr);
  const float wD3r = wDr*SS8F + wDi*CC8F, wD3i = wDi*SS8F - wDr*CC8F;
  DITP(0,8,wDr,wDi)    DITP(1,9,wD1r,wD1i)   DITP(2,10,wD2r,wD2i)  DITP(3,11,wD3r,wD3i)
  DITPM(4,12,wDr,wDi)  DITPM(5,13,wD1r,wD1i) DITPM(6,14,wD2r,wD2i) DITPM(7,15,wD3r,wD3i)
#undef DITP
#undef DITPM
}

// DIF radix-16 inverse butterfly: conj twiddles, levels in reverse order.
__device__ __forceinline__ void dif16(float* xr, float* xi,
    float wAr, float wAi, float wBr, float wBi,
    float wCr, float wCi, float wDr, float wDi)
{
#define DIFP(a, b, wr_, wi_)                                     \
  { const float dr_ = xr[a] - xr[b], di_ = xi[a] - xi[b];        \
    xr[a] = xr[a] + xr[b]; xi[a] = xi[a] + xi[b];                \
    xr[b] = dr_*(wr_) + di_*(wi_);                               \
    xi[b] = di_*(wr_) - dr_*(wi_); }
#define DIFPM(a, b, wr_, wi_)                                    \
  { const float dr_ = xr[a] - xr[b], di_ = xi[a] - xi[b];        \
    xr[a] = xr[a] + xr[b]; xi[a] = xi[a] + xi[b];                \
    const float er_ = dr_*(wr_) + di_*(wi_);                     \
    const float ei_ = di_*(wr_) - dr_*(wi_);                     \
    xr[b] = -ei_; xi[b] = er_; }
  const float wC1r = C45F*(wCr + wCi), wC1i = C45F*(wCi - wCr);
  const float wD1r = wDr*CC8F + wDi*SS8F, wD1i = wDi*CC8F - wDr*SS8F;
  const float wD2r = C45F*(wDr + wDi),    wD2i = C45F*(wDi - wDr);
  const float wD3r = wDr*SS8F + wDi*CC8F, wD3i = wDi*SS8F - wDr*CC8F;
  // L4
  DIFP(0,8,wDr,wDi)    DIFP(1,9,wD1r,wD1i)   DIFP(2,10,wD2r,wD2i)  DIFP(3,11,wD3r,wD3i)
  DIFPM(4,12,wDr,wDi)  DIFPM(5,13,wD1r,wD1i) DIFPM(6,14,wD2r,wD2i) DIFPM(7,15,wD3r,wD3i)
  // L3
  DIFP(0,4,wCr,wCi)   DIFP(1,5,wC1r,wC1i)   DIFPM(2,6,wCr,wCi)   DIFPM(3,7,wC1r,wC1i)
  DIFP(8,12,wCr,wCi)  DIFP(9,13,wC1r,wC1i)  DIFPM(10,14,wCr,wCi) DIFPM(11,15,wC1r,wC1i)
  // L2
  DIFP(0,2,wBr,wBi)   DIFPM(1,3,wBr,wBi)
  DIFP(4,6,wBr,wBi)   DIFPM(5,7,wBr,wBi)
  DIFP(8,10,wBr,wBi)  DIFPM(9,11,wBr,wBi)
  DIFP(12,14,wBr,wBi) DIFPM(13,15,wBr,wBi)
  // L1
  DIFP(0,1,wAr,wAi)   DIFP(2,3,wAr,wAi)   DIFP(4,5,wAr,wAi)   DIFP(6,7,wAr,wAi)
  DIFP(8,9,wAr,wAi)   DIFP(10,11,wAr,wAi) DIFP(12,13,wAr,wAi) DIFP(14,15,wAr,wAi)
#undef DIFP
#undef DIFPM
}

// forward radix-16 LDS pass at stage SS (levels SS..SS+3), butterfly index u
template <int SS>
__device__ __forceinline__ void fwd_pass(u32* S, const float2* __restrict__ tw, int u)
{
  const int j = u & ((1 << SS) - 1);
  const int base = ((u >> SS) << (SS + 4)) | j;
  float xr[16], xi[16];
#pragma unroll
  for (int r = 0; r < 16; r++) {
    const float2 v = up2(S[SWZ(base + (r << SS))]);
    xr[r] = v.x; xi[r] = v.y;
  }
  const float2 wA = tw[j << (12 - SS)];
  const float2 wB = tw[j << (11 - SS)];
  const float2 wC = tw[j << (10 - SS)];
  const float2 wD = tw[j << (9 - SS)];
  dit16(xr, xi, wA.x, wA.y, wB.x, wB.y, wC.x, wC.y, wD.x, wD.y);
#pragma unroll
  for (int r = 0; r < 16; r++)
    S[SWZ(base + (r << SS))] = dn2(xr[r], xi[r]);
}

// inverse radix-16 LDS pass at stage SS (levels SS+3..SS)
template <int SS>
__device__ __forceinline__ void inv_pass(u32* S, const float2* __restrict__ tw, int u)
{
  const int j = u & ((1 << SS) - 1);
  const int base = ((u >> SS) << (SS + 4)) | j;
  float xr[16], xi[16];
#pragma unroll
  for (int r = 0; r < 16; r++) {
    const float2 v = up2(S[SWZ(base + (r << SS))]);
    xr[r] = v.x; xi[r] = v.y;
  }
  const float2 wA = tw[j << (12 - SS)];
  const float2 wB = tw[j << (11 - SS)];
  const float2 wC = tw[j << (10 - SS)];
  const float2 wD = tw[j << (9 - SS)];
  dif16(xr, xi, wA.x, wA.y, wB.x, wB.y, wC.x, wC.y, wD.x, wD.y);
#pragma unroll
  for (int r = 0; r < 16; r++)
    S[SWZ(base + (r << SS))] = dn2(xr[r], xi[r]);
}

// spectral untangle + multiply (ASPEC pre-scaled by 1/8192), register form
__device__ __forceinline__ void mp2(float zr, float zi, float wr, float wi,
                                    float2 a0, float2 a1,
                                    float& okr, float& oki, float& o2r, float& o2i)
{
  const float Xr = 0.5f*(zr + wr), Xi = 0.5f*(zi - wi);
  const float Yr = 0.5f*(zi + wi), Yi = 0.5f*(wr - zr);
  const float Pr = Xr*a0.x - Xi*a0.y, Pi = Xr*a0.y + Xi*a0.x;
  const float Qr = Yr*a1.x - Yi*a1.y, Qi = Yr*a1.y + Yi*a1.x;
  okr = Pr - Qi; oki = Pi + Qr;
  o2r = Pr + Qi; o2i = Qr - Pi;
}

__global__ __launch_bounds__(512, 4) void conv_kernel(
    const u16* __restrict__ vT,       // (8, 512, 4096) bf16
    const float2* __restrict__ aspec, // (512, 4097) pre-scaled
    const float2* __restrict__ tw,
    u16* __restrict__ outT)           // (8, 512, 4096) bf16
{
  __shared__ u32 S[FFTN];             // 32 KB: half2-packed complex
  const int q = blockIdx.x;
  const int b = blockIdx.y;
  const int c0 = 2 * q, c1 = 2 * q + 1;
  const int t = threadIdx.x;
  const int db = (int)(__brev((u32)t) >> 23) << 4;   // 16 * rev9(t)

  // ---- phase 1: coalesced load + forward levels 0-3 (in registers) --------
  {
    const u16* p0 = vT + ((size_t)b * 512 + c0) * 4096;
    const u16* p1 = vT + ((size_t)b * 512 + c1) * 4096;
    float xr[16], xi[16];
#pragma unroll
    for (int it = 0; it < 8; it++) {
      const int r = ((it & 1) << 3) | ((it & 2) << 1) | ((it & 4) >> 1);
      const int jg = t + (it << 9);
      xr[r] = b2f(p0[jg]); xi[r] = b2f(p1[jg]);
    }
#pragma unroll
    for (int m = 0; m < 8; m++) { xr[2*m+1] = 0.f; xi[2*m+1] = 0.f; }
    dit16(xr, xi, 1.f, 0.f, 1.f, 0.f, 1.f, 0.f, 1.f, 0.f);  // j=0: unit twiddles
#pragma unroll
    for (int r = 0; r < 16; r++) S[SWZ(db + r)] = dn2(xr[r], xi[r]);
  }
  __syncthreads();
  // ---- phase 2: forward levels 4-7 (u remapped for conflict-free banks) ---
  fwd_pass<4>(S, tw, ((t & 15) << 5) | (t >> 4));
  __syncthreads();
  // ---- phase 3: forward levels 8-11 ---------------------------------------
  fwd_pass<8>(S, tw, t);
  __syncthreads();
  // ---- phase 4: fwd level 12 + mulpoint + inv level 12, all in registers --
  {
    const float2* A0 = aspec + (size_t)c0 * 4097;
    const float2* A1 = aspec + (size_t)c1 * 4097;
#pragma unroll
    for (int it = 0; it < 4; it++) {
      const int p = t + (it << 9);       // [0, 2048)
      if (it == 0 && t == 0) {
        // special: {0,4096} (self-conjugate) and {2048,6144}
        const int sA = SWZ(0), sB = SWZ(4096), sC = SWZ(2048), sD = SWZ(6144);
        const float2 a = up2(S[sA]), bb = up2(S[sB]);
        const float Z0r = a.x + bb.x, Z0i = a.y + bb.y;
        const float Z4r = a.x - bb.x, Z4i = a.y - bb.y;
        float N0r, N0i, N4r, N4i, u0, u1;
        mp2(Z0r, Z0i, Z0r, Z0i, A0[0], A1[0], N0r, N0i, u0, u1);
        mp2(Z4r, Z4i, Z4r, Z4i, A0[4096], A1[4096], N4r, N4i, u0, u1);
        S[sA] = dn2(N0r + N4r, N0i + N4i);
        S[sB] = dn2(N0r - N4r, N0i - N4i);      // conj(tw[0]) = 1
        const float2 c = up2(S[sC]), e = up2(S[sD]);
        const float2 w2 = tw[2048];
        const float trr = e.x*w2.x - e.y*w2.y, tri = e.x*w2.y + e.y*w2.x;
        const float Z2r = c.x + trr, Z2i = c.y + tri;
        const float Z6r = c.x - trr, Z6i = c.y - tri;
        float N2r, N2i, N6r, N6i;
        mp2(Z2r, Z2i, Z6r, Z6i, A0[2048], A1[2048], N2r, N2i, N6r, N6i);
        const float ddr = N2r - N6r, ddi = N2i - N6i;
        S[sC] = dn2(N2r + N6r, N2i + N6i);
        S[sD] = dn2(ddr*w2.x + ddi*w2.y, ddi*w2.x - ddr*w2.y);
      } else {
        const int p2 = 4096 - p;
        const int s0a = SWZ(p),  s1a = SWZ(p + 4096);
        const int s2a = SWZ(p2), s3a = SWZ(p2 + 4096);
        const float2 a1v = up2(S[s0a]), b1v = up2(S[s1a]);
        const float2 a2v = up2(S[s2a]), b2v = up2(S[s3a]);
        const float2 w1 = tw[p], w2 = tw[p2];
        // forward level 12
        const float t1r = b1v.x*w1.x - b1v.y*w1.y, t1i = b1v.x*w1.y + b1v.y*w1.x;
        const float Zpr = a1v.x + t1r, Zpi = a1v.y + t1i;   // Z[p]
        const float Z4r = a1v.x - t1r, Z4i = a1v.y - t1i;   // Z[p+4096]
        const float t2r = b2v.x*w2.x - b2v.y*w2.y, t2i = b2v.x*w2.y + b2v.y*w2.x;
        const float Zqr = a2v.x + t2r, Zqi = a2v.y + t2i;   // Z[4096-p]
        const float Z8r = a2v.x - t2r, Z8i = a2v.y - t2i;   // Z[8192-p]
        float Npr, Npi, N8r, N8i, Nqr, Nqi, N4r, N4i;
        mp2(Zpr, Zpi, Z8r, Z8i, A0[p],  A1[p],  Npr, Npi, N8r, N8i);  // k=p
        mp2(Zqr, Zqi, Z4r, Z4i, A0[p2], A1[p2], Nqr, Nqi, N4r, N4i);  // k=4096-p
        // inverse level 12
        float dr = Npr - N4r, di = Npi - N4i;
        S[s0a] = dn2(Npr + N4r, Npi + N4i);
        S[s1a] = dn2(dr*w1.x + di*w1.y, di*w1.x - dr*w1.y);
        dr = Nqr - N8r; di = Nqi - N8i;
        S[s2a] = dn2(Nqr + N8r, Nqi + N8i);
        S[s3a] = dn2(dr*w2.x + di*w2.y, di*w2.x - dr*w2.y);
      }
    }
  }
  __syncthreads();
  // ---- phase 5: inverse levels 11-8 ---------------------------------------
  inv_pass<8>(S, tw, t);
  __syncthreads();
  // ---- phase 6: inverse levels 7-4 ----------------------------------------
  inv_pass<4>(S, tw, ((t & 15) << 5) | (t >> 4));
  __syncthreads();
  // ---- phase 7: inverse levels 3-0 + coalesced store ----------------------
  {
    float xr[16], xi[16];
#pragma unroll
    for (int r = 0; r < 16; r++) {
      const float2 v = up2(S[SWZ(db + r)]);
      xr[r] = v.x; xi[r] = v.y;
    }
    dif16(xr, xi, 1.f, 0.f, 1.f, 0.f, 1.f, 0.f, 1.f, 0.f);  // j=0: unit twiddles
    u16* o0 = outT + ((size_t)b * 512 + c0) * 4096;
    u16* o1 = outT + ((size_t)b * 512 + c1) * 4096;
#pragma unroll
    for (int m = 0; m < 8; m++) {
      const int r = 2 * m;
      const int rv = ((r & 2) << 1) | ((r & 4) >> 1) | ((r & 8) >> 3);
      const int i = t + (rv << 9);
      o0[i] = f2b(xr[r]); o1[i] = f2b(xi[r]);
    }
  }
}

// ---------------------------------------------------------------------------
extern "C" void kernel_launch(void* const* d_in, const int* in_sizes, int n_in,
                              void* d_out, int out_size, void* d_ws, size_t ws_size,
                              hipStream_t stream)
{
  const float* x   = (const float*)d_in[0];
  const float* Wu  = (const float*)d_in[1];
  const float* bu  = (const float*)d_in[2];
  const float* Wv  = (const float*)d_in[3];
  const float* bv  = (const float*)d_in[4];
  const float* Wo1 = (const float*)d_in[5];
  const float* bo1 = (const float*)d_in[6];
  const float* Wo2 = (const float*)d_in[7];
  const float* bo2 = (const float*)d_in[8];
  const float* dWp = (const float*)d_in[9];
  const float* dbp = (const float*)d_in[10];
  const float* dW1 = (const float*)d_in[11];
  const float* db1 = (const float*)d_in[12];
  const float* dW2 = (const float*)d_in[13];
  const float* db2 = (const float*)d_in[14];
  const float* dW3 = (const float*)d_in[15];
  const float* db3 = (const float*)d_in[16];
  float* out = (float*)d_out;

  char* wsb = (char*)d_ws;
  const size_t MB = 1u << 20;
  // bf16 weight pool @ 0-6 MB
  u16* WuT  = (u16*)wsb;                    // 1024x512
  u16* WvT  = WuT + 524288;                 // 512x512
  u16* Wo1T = WvT + 262144;                 // 1024x512
  u16* Wo2T = Wo1T + 524288;                // 512x1024
  u16* dW1T = Wo2T + 524288;                // 512x512
  u16* dW2T = dW1T + 262144;
  u16* dW3T = dW2T + 262144;
  // activations / scratch
  u16*    XNb   = (u16*)(wsb + 6 * MB);     // 32768x512 bf16 (dies after u/v)
  u16*    D0b   = (u16*)(wsb + 6 * MB);     // 8192x512 bf16 (over dead XNb)
  float*  D1    = (float*)(wsb + 14 * MB);  // 8192x512 fp32 (DPB hidden layers)
  float*  D1T   = (float*)(wsb + 14 * MB);  // 512x8192 fp32 (final DPB, transposed)
  u16*    CT    = (u16*)(wsb + 6 * MB);     // (8,512,4096) bf16 (after kfft)
  u16*    G     = (u16*)(wsb + 6 * MB);     // 32768x1024 bf16 (after transpose)
  u16*    VTb   = (u16*)(wsb + 38 * MB);    // (8,512,4096) bf16 (dies after conv)
  float2* ASPEC = (float2*)(wsb + 70 * MB); // 512x4097 c64 (~16.8MB)
  float2* TW    = (float2*)(wsb + 87 * MB); // 4096 c64
  u16*    CR    = (u16*)(wsb + 88 * MB);    // 32768x512 bf16
  u16*    U     = (u16*)(wsb + 128 * MB);   // 32768x1024 bf16

  dim3 wt_blk(32, 8);
  // weight transposes + casts
  wtrans_kernel<<<dim3(32, 16), wt_blk, 0, stream>>>(Wu, WuT, 512, 1024);
  wtrans_kernel<<<dim3(16, 16), wt_blk, 0, stream>>>(Wv, WvT, 512, 512);
  wtrans_kernel<<<dim3(32, 16), wt_blk, 0, stream>>>(Wo1, Wo1T, 512, 1024);
  wtrans_kernel<<<dim3(16, 32), wt_blk, 0, stream>>>(Wo2, Wo2T, 1024, 512);
  wtrans_kernel<<<dim3(16, 16), wt_blk, 0, stream>>>(dW1, dW1T, 512, 512);
  wtrans_kernel<<<dim3(16, 16), wt_blk, 0, stream>>>(dW2, dW2T, 512, 512);
  wtrans_kernel<<<dim3(16, 16), wt_blk, 0, stream>>>(dW3, dW3T, 512, 512);
  twiddle_init_kernel<<<8, 512, 0, stream>>>(TW);

  // pre-norm -> bf16
  srms_bf16_kernel<<<8192, 256, 0, stream>>>(x, XNb, 32768, 0);
  // v = silu(xn@Wv+bv) -> VTb channel-major bf16 (fused transpose)
  gemm128x256_bf16_kernel<2><<<dim3(2, 256), 512, 0, stream>>>(XNb, WvT, bv, nullptr, nullptr, VTb, 32768, 512, 512);
  // u = silu(xn@Wu+bu) -> U bf16
  gemm128x256_bf16_kernel<1><<<dim3(4, 256), 512, 0, stream>>>(XNb, WuT, bu, nullptr, nullptr, U, 32768, 1024, 512);

  // DPB MLP -> transposed circulant table D1T (512, 8192) fp32
  dpb0_kernel<<<2048, 256, 0, stream>>>(dWp, dbp, D0b);
  gemm_bf16_kernel<0><<<dim3(4, 64), 256, 0, stream>>>(D0b, dW1T, db1, nullptr, nullptr, D1, 8192, 512, 512);
  srms_bf16_kernel<<<2048, 256, 0, stream>>>(D1, D0b, 8192, 1);
  gemm_bf16_kernel<0><<<dim3(4, 64), 256, 0, stream>>>(D0b, dW2T, db2, nullptr, nullptr, D1, 8192, 512, 512);
  srms_bf16_kernel<<<2048, 256, 0, stream>>>(D1, D0b, 8192, 1);
  gemm_bf16_kernel<5><<<dim3(4, 64), 256, 0, stream>>>(D0b, dW3T, db3, nullptr, nullptr, D1T, 8192, 512, 512);
  // kernel spectra (coalesced rows of D1T), pre-scaled by 1/8192
  kfft_kernel<<<256, 512, 0, stream>>>(D1T, TW, ASPEC);
  // FFT conv: VTb -> CT (bf16, channel-major)
  conv_kernel<<<dim3(256, 8), 512, 0, stream>>>(VTb, ASPEC, TW, CT);
  // CT -> CR row-major bf16
  transpose_b16_kernel<<<dim3(128, 16, 8), wt_blk, 0, stream>>>(CT, CR);
  // gate: (CR@Wo1+bo1)*U -> G bf16
  gemm128x256_bf16_kernel<3><<<dim3(4, 256), 512, 0, stream>>>(CR, Wo1T, bo1, U, nullptr, G, 32768, 1024, 512);
  // final: G@Wo2 + bo2 + x -> out fp32
  gemm128x256_bf16_kernel<4><<<dim3(2, 256), 512, 0, stream>>>(G, Wo2T, bo2, nullptr, x, out, 32768, 512, 1024);
}

// Round 6
// 557.523 us; speedup vs baseline: 1.1644x; 1.1644x over previous
//
#include <hip/hip_runtime.h>
#include <hip/hip_fp16.h>

// ---------------------------------------------------------------------------
// TNO-v2 forward. Round 11: big-GEMM staging switched from global_load_lds
// (64 x 16B @ 1KB stride per wave instr -> request-rate-limited ~1.8 TB/s)
// to register-staged coalesced loads: lanes cover 16 rows x 64B contiguous
// (16 x 64B segments/instr, 4x fewer+larger requests), then ds_write_b128
// into the SAME [kq][row][8] LDS layout -> all read/MFMA/epilogue addressing
// and math order unchanged. T14 split: t+1 loads issue before COMPUTE(t).
// One __syncthreads per iter. Base: r9 (639us, best). dpb GEMMs + conv
// unchanged.
// ---------------------------------------------------------------------------

#define FFTN 8192
#define SWZ(p) ((p) ^ (((p) >> 8) & 31))

#define C45F 0.70710678118654752f
#define CC8F 0.92387953251128676f   /* cos(pi/8) */
#define SS8F 0.38268343236508977f   /* sin(pi/8) */

typedef unsigned short u16;
typedef unsigned int u32;
typedef __attribute__((ext_vector_type(8))) short bf16x8;
typedef __attribute__((ext_vector_type(4))) float f32x4;

__device__ __forceinline__ int brev13(int x) { return (int)(__brev((unsigned)x) >> 19); }
__device__ __forceinline__ float b2f(u16 u) {
  union { float f; u32 i; } c; c.i = ((u32)u) << 16; return c.f;
}
__device__ __forceinline__ u16 f2b(float f) {
  union { float f; u32 i; } c; c.f = f;
  u32 r = c.i + 0x7FFFu + ((c.i >> 16) & 1u);
  return (u16)(r >> 16);
}
__device__ __forceinline__ float silu_f(float x) { return x / (1.f + __expf(-x)); }

// packed half2 <-> 2xfloat
__device__ __forceinline__ float2 up2(u32 v) {
  __half2 h = __builtin_bit_cast(__half2, v);
  return make_float2(__low2float(h), __high2float(h));
}
__device__ __forceinline__ u32 dn2(float r, float i) {
  __half2 h = __floats2half2_rn(r, i);
  return __builtin_bit_cast(u32, h);
}

// async global->LDS, 16B per lane (dpb small-GEMM path only)
__device__ __forceinline__ void gload16(const void* g, void* l) {
  __builtin_amdgcn_global_load_lds(
      (const __attribute__((address_space(1))) u32*)g,
      (__attribute__((address_space(3))) u32*)l, 16, 0, 0);
}

// ---------------- twiddles ---------------------------------------------------
__global__ void twiddle_init_kernel(float2* __restrict__ tw) {
  int k = blockIdx.x * blockDim.x + threadIdx.x;
  if (k < 4096) {
    double ang = -6.283185307179586476925286766559 * ((double)k / 8192.0);
    tw[k] = make_float2((float)cos(ang), (float)sin(ang));
  }
}

// ---------------- SimpleRMSNorm (fp32 in -> bf16 out, optional relu) --------
__global__ __launch_bounds__(256) void srms_bf16_kernel(
    const float* __restrict__ in, u16* __restrict__ out, int rows, int do_relu)
{
  int wave = threadIdx.x >> 6, lane = threadIdx.x & 63;
  int row = (blockIdx.x << 2) + wave;
  if (row >= rows) return;
  const float4* p = (const float4*)(in + (size_t)row * 512);
  float4 a = p[lane], b = p[lane + 64];
  float ss = a.x*a.x + a.y*a.y + a.z*a.z + a.w*a.w
           + b.x*b.x + b.y*b.y + b.z*b.z + b.w*b.w;
#pragma unroll
  for (int off = 32; off > 0; off >>= 1) ss += __shfl_xor(ss, off);
  float inv = 1.0f / (sqrtf(ss) * 0.04419417382415922f + 1e-8f);
  a.x *= inv; a.y *= inv; a.z *= inv; a.w *= inv;
  b.x *= inv; b.y *= inv; b.z *= inv; b.w *= inv;
  if (do_relu) {
    a.x = fmaxf(a.x, 0.f); a.y = fmaxf(a.y, 0.f); a.z = fmaxf(a.z, 0.f); a.w = fmaxf(a.w, 0.f);
    b.x = fmaxf(b.x, 0.f); b.y = fmaxf(b.y, 0.f); b.z = fmaxf(b.z, 0.f); b.w = fmaxf(b.w, 0.f);
  }
  u16* o = out + (size_t)row * 512;
  ushort4 s0, s1;
  s0.x = f2b(a.x); s0.y = f2b(a.y); s0.z = f2b(a.z); s0.w = f2b(a.w);
  s1.x = f2b(b.x); s1.y = f2b(b.y); s1.z = f2b(b.z); s1.w = f2b(b.w);
  *(ushort4*)(o + lane * 4) = s0;
  *(ushort4*)(o + 256 + lane * 4) = s1;
}

// ---------------- DPB layer 0 (bf16 out) ------------------------------------
__global__ __launch_bounds__(256) void dpb0_kernel(
    const float* __restrict__ Wp, const float* __restrict__ bp, u16* __restrict__ out)
{
  int wave = threadIdx.x >> 6, lane = threadIdx.x & 63;
  int row = (blockIdx.x << 2) + wave;   // circulant index 0..8191
  if (row >= 8192) return;
  float pv;
  if (row == 0 || row == 4096) pv = 0.f;
  else if (row < 4096) pv = (float)row;
  else pv = (float)(row - 8192);
  const float4* wp  = (const float4*)Wp;
  const float4* bpp = (const float4*)bp;
  float4 a = wp[lane], b = wp[lane + 64];
  float4 c = bpp[lane], d = bpp[lane + 64];
  a.x = fmaf(pv, a.x, c.x); a.y = fmaf(pv, a.y, c.y);
  a.z = fmaf(pv, a.z, c.z); a.w = fmaf(pv, a.w, c.w);
  b.x = fmaf(pv, b.x, d.x); b.y = fmaf(pv, b.y, d.y);
  b.z = fmaf(pv, b.z, d.z); b.w = fmaf(pv, b.w, d.w);
  float ss = a.x*a.x + a.y*a.y + a.z*a.z + a.w*a.w
           + b.x*b.x + b.y*b.y + b.z*b.z + b.w*b.w;
#pragma unroll
  for (int off = 32; off > 0; off >>= 1) ss += __shfl_xor(ss, off);
  float inv = 1.0f / (sqrtf(ss) * 0.04419417382415922f + 1e-8f);
  u16* o = out + (size_t)row * 512;
  ushort4 s0, s1;
  s0.x = f2b(fmaxf(a.x * inv, 0.f)); s0.y = f2b(fmaxf(a.y * inv, 0.f));
  s0.z = f2b(fmaxf(a.z * inv, 0.f)); s0.w = f2b(fmaxf(a.w * inv, 0.f));
  s1.x = f2b(fmaxf(b.x * inv, 0.f)); s1.y = f2b(fmaxf(b.y * inv, 0.f));
  s1.z = f2b(fmaxf(b.z * inv, 0.f)); s1.w = f2b(fmaxf(b.w * inv, 0.f));
  *(ushort4*)(o + lane * 4) = s0;
  *(ushort4*)(o + 256 + lane * 4) = s1;
}

// ---------------- weight transpose+cast: fp32 (R,C) -> bf16 (C,R) -----------
__global__ __launch_bounds__(256) void wtrans_kernel(
    const float* __restrict__ in, u16* __restrict__ out, int R, int C)
{
  __shared__ float tile[32][33];
  const int c0 = blockIdx.x << 5, r0 = blockIdx.y << 5;
  const int tx = threadIdx.x, ty = threadIdx.y;
#pragma unroll
  for (int i = 0; i < 32; i += 8)
    tile[ty + i][tx] = in[(size_t)(r0 + ty + i) * C + c0 + tx];
  __syncthreads();
#pragma unroll
  for (int i = 0; i < 32; i += 8)
    out[(size_t)(c0 + ty + i) * R + r0 + tx] = f2b(tile[tx][ty + i]);
}

// ---------------- bf16 transpose: (8, 512, 4096) -> (8, 4096, 512) ----------
__global__ __launch_bounds__(256) void transpose_b16_kernel(
    const u16* __restrict__ in, u16* __restrict__ out)
{
  __shared__ u16 tile[32][33];
  const int b = blockIdx.z;
  const int j0 = blockIdx.x << 5, c0 = blockIdx.y << 5;
  const int tx = threadIdx.x, ty = threadIdx.y;
  const u16* ip = in + ((size_t)b << 21);
  u16* op = out + ((size_t)b << 21);
#pragma unroll
  for (int i = 0; i < 32; i += 8)
    tile[ty + i][tx] = ip[(size_t)(c0 + ty + i) * 4096 + j0 + tx];
  __syncthreads();
#pragma unroll
  for (int i = 0; i < 32; i += 8)
    op[(size_t)(j0 + ty + i) * 512 + c0 + tx] = tile[tx][ty + i];
}

// ---------------- MFMA bf16 GEMM (r6 2-phase, 128x128 tile) -----------------
// Used for the small dpb GEMMs only.  EPI: 0 plain fp32 | 5 fp32 C^T
template <int EPI>
__global__ __launch_bounds__(256) void gemm_bf16_kernel(
    const u16* __restrict__ A, const u16* __restrict__ Bt,
    const float* __restrict__ bias, const u16* __restrict__ aux16,
    const float* __restrict__ auxf, void* __restrict__ Cv,
    int M, int N, int K)
{
  __shared__ __align__(16) u16 As[4096];   // [khalf(4)][m(128)][8 bf16]
  __shared__ __align__(16) u16 Bs[4096];   // [khalf(4)][n(128)][8 bf16]
  const int tid = threadIdx.x;
  const int lane = tid & 63;
  const int w = tid >> 6;
  const int wm = (w >> 1) << 6;
  const int wn = (w & 1) << 6;
  const int lm = lane & 15;
  const int lq = lane >> 4;
  const int bm = blockIdx.y << 7;
  const int bn = blockIdx.x << 7;

  const int sm = tid & 127;     // staging row within tile
  const int sk = tid >> 7;      // 0/1 -> khalf sk (phase 0) and 2+sk (phase 1)
  const u16* Ap = A + (size_t)(bm + sm) * K + sk * 8;
  const u16* Bp = Bt + (size_t)(bn + sm) * K + sk * 8;
  u16* As0 = As + ((sk)     * 128 + sm) * 8;
  u16* As1 = As + ((2 + sk) * 128 + sm) * 8;
  u16* Bs0 = Bs + ((sk)     * 128 + sm) * 8;
  u16* Bs1 = Bs + ((2 + sk) * 128 + sm) * 8;

  f32x4 acc[4][4];
#pragma unroll
  for (int i = 0; i < 4; i++)
#pragma unroll
    for (int j = 0; j < 4; j++) acc[i][j] = (f32x4){0.f, 0.f, 0.f, 0.f};

  for (int k0 = 0; k0 < K; k0 += 32) {
    __syncthreads();                       // prior tile fully consumed
    gload16(Ap, As0); gload16(Ap + 16, As1);
    gload16(Bp, Bs0); gload16(Bp + 16, Bs1);
    Ap += 32; Bp += 32;
    __builtin_amdgcn_s_waitcnt(0);         // drain global_load_lds
    __syncthreads();
    bf16x8 af[4], bfr[4];
#pragma unroll
    for (int i = 0; i < 4; i++) {
      af[i]  = *(const bf16x8*)(As + (lq * 128 + wm + i * 16 + lm) * 8);
      bfr[i] = *(const bf16x8*)(Bs + (lq * 128 + wn + i * 16 + lm) * 8);
    }
#pragma unroll
    for (int i = 0; i < 4; i++)
#pragma unroll
      for (int j = 0; j < 4; j++)
        acc[i][j] = __builtin_amdgcn_mfma_f32_16x16x32_bf16(af[i], bfr[j], acc[i][j], 0, 0, 0);
  }

  // epilogue: lane holds C[m0 + r][n] for r=0..3 per (i,j) tile
#pragma unroll
  for (int i = 0; i < 4; i++) {
    const int m0 = bm + wm + i * 16 + lq * 4;
#pragma unroll
    for (int j = 0; j < 4; j++) {
      const int n = bn + wn + j * 16 + lm;
      const float bb = bias[n];
      const f32x4 v = acc[i][j];
      if constexpr (EPI == 5) {
        // C^T[n][m] fp32, rows r consecutive in m
        float4 o = make_float4(v[0] + bb, v[1] + bb, v[2] + bb, v[3] + bb);
        *(float4*)((float*)Cv + (size_t)n * M + m0) = o;
      } else {
#pragma unroll
        for (int r = 0; r < 4; r++) {
          const size_t idx = (size_t)(m0 + r) * N + n;
          const float val = v[r] + bb;
          if constexpr (EPI == 0) ((float*)Cv)[idx] = val;
          if constexpr (EPI == 1) ((u16*)Cv)[idx] = f2b(silu_f(val));
          if constexpr (EPI == 3) ((u16*)Cv)[idx] = f2b(val * b2f(aux16[idx]));
          if constexpr (EPI == 4) ((float*)Cv)[idx] = val + auxf[idx];
        }
      }
    }
  }
}

// ---------------- MFMA bf16 GEMM, 128x256 tile, BK=32, reg-staged -----------
// EPI: 1 silu bf16 | 2 silu bf16 transposed (VT: b,c,j) | 3 gate | 4 +auxf fp32
// Requires M%128==0, N%256==0, K%32==0, K>=64.
// Staging: thread (srow=tid>>2, skc=tid&3) -> lanes cover 16 rows x 64B
// CONTIGUOUS per instruction (16x64B segments, vs gload_lds's 64x16B@1KB
// stride). ds_write_b128 into the same [kq(4)][row(128)][8] layout ->
// ds_read/MFMA/epilogue identical to r9. Double-buffered 48KB, 2 blocks/CU,
// acc[4][4]=64 VGPR, 8 waves (2M x 4N). t+1 loads issue before COMPUTE(t);
// compiler inserts the vmcnt before the dependent ds_write (~600cy later).
// Single __syncthreads per iter (write target was last read before the
// previous barrier).
template <int EPI>
__global__ __launch_bounds__(512, 4) void gemm128x256_bf16_kernel(
    const u16* __restrict__ A, const u16* __restrict__ Bt,
    const float* __restrict__ bias, const u16* __restrict__ aux16,
    const float* __restrict__ auxf, void* __restrict__ Cv,
    int M, int N, int K)
{
  __shared__ __align__(16) u16 Asm[2][4096];   // 2 x 8 KB  [kq][row][8]
  __shared__ __align__(16) u16 Bsm[2][8192];   // 2 x 16 KB [h][kq][row][8]
  const int tid = threadIdx.x;          // 0..511
  const int lane = tid & 63;
  const int w = tid >> 6;               // 0..7 waves (2M x 4N)
  const int wm = (w >> 2) << 6;         // 0,64
  const int wn = (w & 3) << 6;          // 0,64,128,192
  const int lm = lane & 15;
  const int lq = lane >> 4;             // 0..3
  const int bm = blockIdx.y << 7;
  const int bn = blockIdx.x << 8;

  // coalesced staging: thread -> (srow = tid>>2, skc = tid&3)
  const int srow = tid >> 2;            // 0..127
  const int skc  = tid & 3;             // 16B chunk within the 64B k-tile row
  const u16* AgC  = A  + (size_t)(bm + srow) * K + skc * 8;
  const u16* BgC0 = Bt + (size_t)(bn + srow) * K + skc * 8;
  const u16* BgC1 = Bt + (size_t)(bn + 128 + srow) * K + skc * 8;
  const int ldst = (skc * 128 + srow) * 8;   // u16 offset within buffer plane

  f32x4 acc[4][4];
#pragma unroll
  for (int i = 0; i < 4; i++)
#pragma unroll
    for (int j = 0; j < 4; j++) acc[i][j] = (f32x4){0.f, 0.f, 0.f, 0.f};

#define COMPUTE(buf) do {                                             \
    const u16* cA = &Asm[buf][0];                                     \
    const u16* cB = &Bsm[buf][0];                                     \
    bf16x8 bfr[4];                                                    \
    _Pragma("unroll")                                                 \
    for (int j = 0; j < 4; ++j) {                                     \
      const int c = wn + j * 16 + lm;                                 \
      bfr[j] = *(const bf16x8*)(cB + (c >> 7) * 4096 + lq * 1024 + (c & 127) * 8); \
    }                                                                 \
    _Pragma("unroll")                                                 \
    for (int qm = 0; qm < 2; ++qm) {                                  \
      bf16x8 af[2];                                                   \
      _Pragma("unroll")                                               \
      for (int i2 = 0; i2 < 2; ++i2)                                  \
        af[i2] = *(const bf16x8*)(cA + lq * 1024 + (wm + qm * 32 + i2 * 16 + lm) * 8); \
      __builtin_amdgcn_s_setprio(1);                                  \
      _Pragma("unroll")                                               \
      for (int i2 = 0; i2 < 2; ++i2)                                  \
        _Pragma("unroll")                                             \
        for (int j = 0; j < 4; ++j)                                   \
          acc[qm * 2 + i2][j] = __builtin_amdgcn_mfma_f32_16x16x32_bf16( \
              af[i2], bfr[j], acc[qm * 2 + i2][j], 0, 0, 0);          \
      __builtin_amdgcn_s_setprio(0);                                  \
    }                                                                 \
  } while (0)

  // prologue: tile 0 -> regs -> buffer 0
  uint4 ra  = *(const uint4*)(AgC);
  uint4 rb0 = *(const uint4*)(BgC0);
  uint4 rb1 = *(const uint4*)(BgC1);
  *(uint4*)(&Asm[0][0] + ldst) = ra;
  *(uint4*)(&Bsm[0][0] + ldst) = rb0;
  *(uint4*)(&Bsm[0][0] + 4096 + ldst) = rb1;
  __syncthreads();

  const int NT = K >> 5;
  int cur = 0;
  for (int t = 0; t < NT; ++t) {
    if (t + 1 < NT) {                       // issue t+1 loads (fly under MFMA)
      ra  = *(const uint4*)(AgC  + (size_t)(t + 1) * 32);
      rb0 = *(const uint4*)(BgC0 + (size_t)(t + 1) * 32);
      rb1 = *(const uint4*)(BgC1 + (size_t)(t + 1) * 32);
    }
    COMPUTE(cur);
    if (t + 1 < NT) {                       // write t+1 into the other buffer
      const int nb = cur ^ 1;
      *(uint4*)(&Asm[nb][0] + ldst) = ra;
      *(uint4*)(&Bsm[nb][0] + ldst) = rb0;
      *(uint4*)(&Bsm[nb][0] + 4096 + ldst) = rb1;
    }
    __syncthreads();                        // writes visible; reads of cur done
    cur ^= 1;
  }
#undef COMPUTE

  // epilogue
#pragma unroll
  for (int i = 0; i < 4; i++) {
    const int m0 = bm + wm + i * 16 + lq * 4;
#pragma unroll
    for (int j = 0; j < 4; j++) {
      const int n = bn + wn + j * 16 + lm;
      const float bb = bias[n];
      const f32x4 v = acc[i][j];
      if constexpr (EPI == 2) {
        const int b = m0 >> 12;
        const int jq = m0 & 4095;
        ushort4 s;
        s.x = f2b(silu_f(v[0] + bb)); s.y = f2b(silu_f(v[1] + bb));
        s.z = f2b(silu_f(v[2] + bb)); s.w = f2b(silu_f(v[3] + bb));
        *(ushort4*)((u16*)Cv + (((size_t)(b * 512 + n)) << 12) + jq) = s;
      } else {
#pragma unroll
        for (int r = 0; r < 4; r++) {
          const size_t idx = (size_t)(m0 + r) * N + n;
          const float val = v[r] + bb;
          if constexpr (EPI == 1) ((u16*)Cv)[idx] = f2b(silu_f(val));
          if constexpr (EPI == 3) ((u16*)Cv)[idx] = f2b(val * b2f(aux16[idx]));
          if constexpr (EPI == 4) ((float*)Cv)[idx] = val + auxf[idx];
        }
      }
    }
  }
}

// ============================================================================
// fp32 FFT core (kfft only)
// ============================================================================
__device__ __forceinline__ void fft8192_dit(float* sr, float* si,
                                            const float2* __restrict__ tw)
{
  const int t = threadIdx.x;
  for (int s = 0; s < 12; s += 2) {
    __syncthreads();
    const int h = 1 << s;
#pragma unroll
    for (int bb = 0; bb < 4; bb++) {
      const int u = t + (bb << 9);
      const int j = u & (h - 1);
      const int base = ((u >> s) << (s + 2)) | j;
      const float2 w1 = tw[j << (12 - s)];
      const float2 w2 = tw[j << (11 - s)];
      const int q0 = SWZ(base), q1 = SWZ(base + h);
      const int q2 = SWZ(base + 2 * h), q3 = SWZ(base + 3 * h);
      const float ar = sr[q0], ai = si[q0];
      const float br = sr[q1], bi = si[q1];
      const float cr = sr[q2], ci = si[q2];
      const float dr = sr[q3], di = si[q3];
      const float t1r = br * w1.x - bi * w1.y, t1i = br * w1.y + bi * w1.x;
      const float t2r = dr * w1.x - di * w1.y, t2i = dr * w1.y + di * w1.x;
      const float Ar = ar + t1r, Ai = ai + t1i;
      const float Br = ar - t1r, Bi = ai - t1i;
      const float Cr = cr + t2r, Ci = ci + t2i;
      const float Dr = cr - t2r, Di = ci - t2i;
      const float t3r = Cr * w2.x - Ci * w2.y, t3i = Cr * w2.y + Ci * w2.x;
      const float pr  = Dr * w2.x - Di * w2.y, pi  = Dr * w2.y + Di * w2.x;
      const float t4r = pi, t4i = -pr;
      sr[q0] = Ar + t3r; si[q0] = Ai + t3i;
      sr[q2] = Ar - t3r; si[q2] = Ai - t3i;
      sr[q1] = Br + t4r; si[q1] = Bi + t4i;
      sr[q3] = Br - t4r; si[q3] = Bi - t4i;
    }
  }
  __syncthreads();
#pragma unroll
  for (int bb = 0; bb < 8; bb++) {
    const int u = t + (bb << 9);
    const float2 w = tw[u];
    const int p0 = SWZ(u), p1 = SWZ(u + 4096);
    const float br = sr[p1], bi = si[p1];
    const float trr = br * w.x - bi * w.y;
    const float tri = br * w.y + bi * w.x;
    const float ar = sr[p0], ai = si[p0];
    sr[p0] = ar + trr; si[p0] = ai + tri;
    sr[p1] = ar - trr; si[p1] = ai - tri;
  }
  __syncthreads();
}

// ---------------- kernel spectra (fp32, reads transposed D1T coalesced) -----
__global__ __launch_bounds__(512) void kfft_kernel(
    const float* __restrict__ D1T,    // (512, 8192) fp32
    const float2* __restrict__ tw,
    float2* __restrict__ aspec)
{
  __shared__ float sr[FFTN];
  __shared__ float si[FFTN];
  const int q = blockIdx.x;
  const int t = threadIdx.x;
  const float* row0 = D1T + ((size_t)(2 * q)) * 8192;
  const float* row1 = row0 + 8192;
#pragma unroll
  for (int it = 0; it < 16; it++) {
    const int r = t + (it << 9);
    const int d = SWZ(brev13(r));
    sr[d] = row0[r]; si[d] = row1[r];
  }
  fft8192_dit(sr, si, tw);
  // fold inverse-FFT 1/8192 scale into the spectra
  const float sc = 1.0f / 8192.0f;
  float2* O0 = aspec + (size_t)(2 * q) * 4097;
  float2* O1 = aspec + (size_t)(2 * q + 1) * 4097;
#pragma unroll 1
  for (int it = 0; it < 8; it++) {
    const int k = t + (it << 9);
    const int k2 = (FFTN - k) & (FFTN - 1);
    const float zr = sr[SWZ(k)],  zi = si[SWZ(k)];
    const float wr = sr[SWZ(k2)], wi = si[SWZ(k2)];
    O0[k] = make_float2(0.5f * sc * (zr + wr), 0.5f * sc * (zi - wi));
    O1[k] = make_float2(0.5f * sc * (zi + wi), 0.5f * sc * (wr - zr));
  }
  if (t == 0) {
    const float zr = sr[SWZ(4096)], zi = si[SWZ(4096)];
    O0[4096] = make_float2(zr * sc, 0.f);
    O1[4096] = make_float2(zi * sc, 0.f);
  }
}

// ============================================================================
// conv: radix-16 register-butterfly FFT, half2 LDS storage (fp32 math)
// ============================================================================

// DIT radix-16 butterfly (levels of distance 1,2,4,8 within x[16]).
__device__ __forceinline__ void dit16(float* xr, float* xi,
    float wAr, float wAi, float wBr, float wBi,
    float wCr, float wCi, float wDr, float wDi)
{
#define DITP(a, b, wr_, wi_)                                     \
  { const float cr_ = xr[b]*(wr_) - xi[b]*(wi_);                 \
    const float ci_ = xr[b]*(wi_) + xi[b]*(wr_);                 \
    xr[b] = xr[a] - cr_; xi[b] = xi[a] - ci_;                    \
    xr[a] = xr[a] + cr_; xi[a] = xi[a] + ci_; }
#define DITPM(a, b, wr_, wi_)                                    \
  { const float cr_ = xr[b]*(wr_) - xi[b]*(wi_);                 \
    const float ci_ = xr[b]*(wi_) + xi[b]*(wr_);                 \
    xr[b] = xr[a] - ci_; xi[b] = xi[a] + cr_;                    \
    xr[a] = xr[a] + ci_; xi[a] = xi[a] - cr_; }
  // L1 (distance 1): all pairs share wA
  DITP(0,1,wAr,wAi)   DITP(2,3,wAr,wAi)   DITP(4,5,wAr,wAi)   DITP(6,7,wAr,wAi)
  DITP(8,9,wAr,wAi)   DITP(10,11,wAr,wAi) DITP(12,13,wAr,wAi) DITP(14,15,wAr,wAi)
  // L2 (distance 2): q=0 -> wB, q=1 -> wB*(-i)
  DITP(0,2,wBr,wBi)   DITPM(1,3,wBr,wBi)
  DITP(4,6,wBr,wBi)   DITPM(5,7,wBr,wBi)
  DITP(8,10,wBr,wBi)  DITPM(9,11,wBr,wBi)
  DITP(12,14,wBr,wBi) DITPM(13,15,wBr,wBi)
  // L3 (distance 4): q -> wC * e^{-i pi q/4}
  const float wC1r = C45F*(wCr + wCi), wC1i = C45F*(wCi - wCr);
  DITP(0,4,wCr,wCi)   DITP(1,5,wC1r,wC1i)   DITPM(2,6,wCr,wCi)   DITPM(3,7,wC1r,wC1i)
  DITP(8,12,wCr,wCi)  DITP(9,13,wC1r,wC1i)  DITPM(10,14,wCr,wCi) DITPM(11,15,wC1r,wC1i)
  // L4 (distance 8): q -> wD * e^{-i pi q/8}
  const float wD1r = wDr*CC8F + wDi*SS8F, wD1i = wDi*CC8F - wDr*SS8F;
  const float wD2r = C45F*(wDr + wDi),    wD2i = C45F*(wDi - wDr);
  const float wD3r = wDr*SS8F + wDi*CC8F, wD3i = wDi*SS8F - wDr*CC8F;
  DITP(0,8,wDr,wDi)    DITP(1,9,wD1r,wD1i)   DITP(2,10,wD2r,wD2i)  DITP(3,11,wD3r,wD3i)
  DITPM(4,12,wDr,wDi)  DITPM(5,13,wD1r,wD1i) DITPM(6,14,wD2r,wD2i) DITPM(7,15,wD3r,wD3i)
#undef DITP
#undef DITPM
}

// DIF radix-16 inverse butterfly: conj twiddles, levels in reverse order.
__device__ __forceinline__ void dif16(float* xr, float* xi,
    float wAr, float wAi, float wBr, float wBi,
    float wCr, float wCi, float wDr, float wDi)
{
#define DIFP(a, b, wr_, wi_)                                     \
  { const float dr_ = xr[a] - xr[b], di_ = xi[a] - xi[b];        \
    xr[a] = xr[a] + xr[b]; xi[a] = xi[a] + xi[b];                \
    xr[b] = dr_*(wr_) + di_*(wi_);                               \
    xi[b] = di_*(wr_) - dr_*(wi_); }
#define DIFPM(a, b, wr_, wi_)                                    \
  { const float dr_ = xr[a] - xr[b], di_ = xi[a] - xi[b];        \
    xr[a] = xr[a] + xr[b]; xi[a] = xi[a] + xi[b];                \
    const float er_ = dr_*(wr_) + di_*(wi_);                     \
    const float ei_ = di_*(wr_) - dr_*(wi_);                     \
    xr[b] = -ei_; xi[b] = er_; }
  const float wC1r = C45F*(wCr + wCi), wC1i = C45F*(wCi - wCr);
  const float wD1r = wDr*CC8F + wDi*SS8F, wD1i = wDi*CC8F - wDr*SS8F;
  const float wD2r = C45F*(wDr + wDi),    wD2i = C45F*(wDi - wDr);
  const float wD3r = wDr*SS8F + wDi*CC8F, wD3i = wDi*SS8F - wDr*CC8F;
  // L4
  DIFP(0,8,wDr,wDi)    DIFP(1,9,wD1r,wD1i)   DIFP(2,10,wD2r,wD2i)  DIFP(3,11,wD3r,wD3i)
  DIFPM(4,12,wDr,wDi)  DIFPM(5,13,wD1r,wD1i) DIFPM(6,14,wD2r,wD2i) DIFPM(7,15,wD3r,wD3i)
  // L3
  DIFP(0,4,wCr,wCi)   DIFP(1,5,wC1r,wC1i)   DIFPM(2,6,wCr,wCi)   DIFPM(3,7,wC1r,wC1i)
  DIFP(8,12,wCr,wCi)  DIFP(9,13,wC1r,wC1i)  DIFPM(10,14,wCr,wCi) DIFPM(11,15,wC1r,wC1i)
  // L2
  DIFP(0,2,wBr,wBi)   DIFPM(1,3,wBr,wBi)
  DIFP(4,6,wBr,wBi)   DIFPM(5,7,wBr,wBi)
  DIFP(8,10,wBr,wBi)  DIFPM(9,11,wBr,wBi)
  DIFP(12,14,wBr,wBi) DIFPM(13,15,wBr,wBi)
  // L1
  DIFP(0,1,wAr,wAi)   DIFP(2,3,wAr,wAi)   DIFP(4,5,wAr,wAi)   DIFP(6,7,wAr,wAi)
  DIFP(8,9,wAr,wAi)   DIFP(10,11,wAr,wAi) DIFP(12,13,wAr,wAi) DIFP(14,15,wAr,wAi)
#undef DIFP
#undef DIFPM
}

// forward radix-16 LDS pass at stage SS (levels SS..SS+3), butterfly index u
template <int SS>
__device__ __forceinline__ void fwd_pass(u32* S, const float2* __restrict__ tw, int u)
{
  const int j = u & ((1 << SS) - 1);
  const int base = ((u >> SS) << (SS + 4)) | j;
  float xr[16], xi[16];
#pragma unroll
  for (int r = 0; r < 16; r++) {
    const float2 v = up2(S[SWZ(base + (r << SS))]);
    xr[r] = v.x; xi[r] = v.y;
  }
  const float2 wA = tw[j << (12 - SS)];
  const float2 wB = tw[j << (11 - SS)];
  const float2 wC = tw[j << (10 - SS)];
  const float2 wD = tw[j << (9 - SS)];
  dit16(xr, xi, wA.x, wA.y, wB.x, wB.y, wC.x, wC.y, wD.x, wD.y);
#pragma unroll
  for (int r = 0; r < 16; r++)
    S[SWZ(base + (r << SS))] = dn2(xr[r], xi[r]);
}

// inverse radix-16 LDS pass at stage SS (levels SS+3..SS)
template <int SS>
__device__ __forceinline__ void inv_pass(u32* S, const float2* __restrict__ tw, int u)
{
  const int j = u & ((1 << SS) - 1);
  const int base = ((u >> SS) << (SS + 4)) | j;
  float xr[16], xi[16];
#pragma unroll
  for (int r = 0; r < 16; r++) {
    const float2 v = up2(S[SWZ(base + (r << SS))]);
    xr[r] = v.x; xi[r] = v.y;
  }
  const float2 wA = tw[j << (12 - SS)];
  const float2 wB = tw[j << (11 - SS)];
  const float2 wC = tw[j << (10 - SS)];
  const float2 wD = tw[j << (9 - SS)];
  dif16(xr, xi, wA.x, wA.y, wB.x, wB.y, wC.x, wC.y, wD.x, wD.y);
#pragma unroll
  for (int r = 0; r < 16; r++)
    S[SWZ(base + (r << SS))] = dn2(xr[r], xi[r]);
}

// spectral untangle + multiply (ASPEC pre-scaled by 1/8192), register form
__device__ __forceinline__ void mp2(float zr, float zi, float wr, float wi,
                                    float2 a0, float2 a1,
                                    float& okr, float& oki, float& o2r, float& o2i)
{
  const float Xr = 0.5f*(zr + wr), Xi = 0.5f*(zi - wi);
  const float Yr = 0.5f*(zi + wi), Yi = 0.5f*(wr - zr);
  const float Pr = Xr*a0.x - Xi*a0.y, Pi = Xr*a0.y + Xi*a0.x;
  const float Qr = Yr*a1.x - Yi*a1.y, Qi = Yr*a1.y + Yi*a1.x;
  okr = Pr - Qi; oki = Pi + Qr;
  o2r = Pr + Qi; o2i = Qr - Pi;
}

__global__ __launch_bounds__(512, 4) void conv_kernel(
    const u16* __restrict__ vT,       // (8, 512, 4096) bf16
    const float2* __restrict__ aspec, // (512, 4097) pre-scaled
    const float2* __restrict__ tw,
    u16* __restrict__ outT)           // (8, 512, 4096) bf16
{
  __shared__ u32 S[FFTN];             // 32 KB: half2-packed complex
  const int q = blockIdx.x;
  const int b = blockIdx.y;
  const int c0 = 2 * q, c1 = 2 * q + 1;
  const int t = threadIdx.x;
  const int db = (int)(__brev((u32)t) >> 23) << 4;   // 16 * rev9(t)

  // ---- phase 1: coalesced load + forward levels 0-3 (in registers) --------
  {
    const u16* p0 = vT + ((size_t)b * 512 + c0) * 4096;
    const u16* p1 = vT + ((size_t)b * 512 + c1) * 4096;
    float xr[16], xi[16];
#pragma unroll
    for (int it = 0; it < 8; it++) {
      const int r = ((it & 1) << 3) | ((it & 2) << 1) | ((it & 4) >> 1);
      const int jg = t + (it << 9);
      xr[r] = b2f(p0[jg]); xi[r] = b2f(p1[jg]);
    }
#pragma unroll
    for (int m = 0; m < 8; m++) { xr[2*m+1] = 0.f; xi[2*m+1] = 0.f; }
    dit16(xr, xi, 1.f, 0.f, 1.f, 0.f, 1.f, 0.f, 1.f, 0.f);  // j=0: unit twiddles
#pragma unroll
    for (int r = 0; r < 16; r++) S[SWZ(db + r)] = dn2(xr[r], xi[r]);
  }
  __syncthreads();
  // ---- phase 2: forward levels 4-7 (u remapped for conflict-free banks) ---
  fwd_pass<4>(S, tw, ((t & 15) << 5) | (t >> 4));
  __syncthreads();
  // ---- phase 3: forward levels 8-11 ---------------------------------------
  fwd_pass<8>(S, tw, t);
  __syncthreads();
  // ---- phase 4: fwd level 12 + mulpoint + inv level 12, all in registers --
  {
    const float2* A0 = aspec + (size_t)c0 * 4097;
    const float2* A1 = aspec + (size_t)c1 * 4097;
#pragma unroll
    for (int it = 0; it < 4; it++) {
      const int p = t + (it << 9);       // [0, 2048)
      if (it == 0 && t == 0) {
        // special: {0,4096} (self-conjugate) and {2048,6144}
        const int sA = SWZ(0), sB = SWZ(4096), sC = SWZ(2048), sD = SWZ(6144);
        const float2 a = up2(S[sA]), bb = up2(S[sB]);
        const float Z0r = a.x + bb.x, Z0i = a.y + bb.y;
        const float Z4r = a.x - bb.x, Z4i = a.y - bb.y;
        float N0r, N0i, N4r, N4i, u0, u1;
        mp2(Z0r, Z0i, Z0r, Z0i, A0[0], A1[0], N0r, N0i, u0, u1);
        mp2(Z4r, Z4i, Z4r, Z4i, A0[4096], A1[4096], N4r, N4i, u0, u1);
        S[sA] = dn2(N0r + N4r, N0i + N4i);
        S[sB] = dn2(N0r - N4r, N0i - N4i);      // conj(tw[0]) = 1
        const float2 c = up2(S[sC]), e = up2(S[sD]);
        const float2 w2 = tw[2048];
        const float trr = e.x*w2.x - e.y*w2.y, tri = e.x*w2.y + e.y*w2.x;
        const float Z2r = c.x + trr, Z2i = c.y + tri;
        const float Z6r = c.x - trr, Z6i = c.y - tri;
        float N2r, N2i, N6r, N6i;
        mp2(Z2r, Z2i, Z6r, Z6i, A0[2048], A1[2048], N2r, N2i, N6r, N6i);
        const float ddr = N2r - N6r, ddi = N2i - N6i;
        S[sC] = dn2(N2r + N6r, N2i + N6i);
        S[sD] = dn2(ddr*w2.x + ddi*w2.y, ddi*w2.x - ddr*w2.y);
      } else {
        const int p2 = 4096 - p;
        const int s0a = SWZ(p),  s1a = SWZ(p + 4096);
        const int s2a = SWZ(p2), s3a = SWZ(p2 + 4096);
        const float2 a1v = up2(S[s0a]), b1v = up2(S[s1a]);
        const float2 a2v = up2(S[s2a]), b2v = up2(S[s3a]);
        const float2 w1 = tw[p], w2 = tw[p2];
        // forward level 12
        const float t1r = b1v.x*w1.x - b1v.y*w1.y, t1i = b1v.x*w1.y + b1v.y*w1.x;
        const float Zpr = a1v.x + t1r, Zpi = a1v.y + t1i;   // Z[p]
        const float Z4r = a1v.x - t1r, Z4i = a1v.y - t1i;   // Z[p+4096]
        const float t2r = b2v.x*w2.x - b2v.y*w2.y, t2i = b2v.x*w2.y + b2v.y*w2.x;
        const float Zqr = a2v.x + t2r, Zqi = a2v.y + t2i;   // Z[4096-p]
        const float Z8r = a2v.x - t2r, Z8i = a2v.y - t2i;   // Z[8192-p]
        float Npr, Npi, N8r, N8i, Nqr, Nqi, N4r, N4i;
        mp2(Zpr, Zpi, Z8r, Z8i, A0[p],  A1[p],  Npr, Npi, N8r, N8i);  // k=p
        mp2(Zqr, Zqi, Z4r, Z4i, A0[p2], A1[p2], Nqr, Nqi, N4r, N4i);  // k=4096-p
        // inverse level 12
        float dr = Npr - N4r, di = Npi - N4i;
        S[s0a] = dn2(Npr + N4r, Npi + N4i);
        S[s1a] = dn2(dr*w1.x + di*w1.y, di*w1.x - dr*w1.y);
        dr = Nqr - N8r; di = Nqi - N8i;
        S[s2a] = dn2(Nqr + N8r, Nqi + N8i);
        S[s3a] = dn2(dr*w2.x + di*w2.y, di*w2.x - dr*w2.y);
      }
    }
  }
  __syncthreads();
  // ---- phase 5: inverse levels 11-8 ---------------------------------------
  inv_pass<8>(S, tw, t);
  __syncthreads();
  // ---- phase 6: inverse levels 7-4 ----------------------------------------
  inv_pass<4>(S, tw, ((t & 15) << 5) | (t >> 4));
  __syncthreads();
  // ---- phase 7: inverse levels 3-0 + coalesced store ----------------------
  {
    float xr[16], xi[16];
#pragma unroll
    for (int r = 0; r < 16; r++) {
      const float2 v = up2(S[SWZ(db + r)]);
      xr[r] = v.x; xi[r] = v.y;
    }
    dif16(xr, xi, 1.f, 0.f, 1.f, 0.f, 1.f, 0.f, 1.f, 0.f);  // j=0: unit twiddles
    u16* o0 = outT + ((size_t)b * 512 + c0) * 4096;
    u16* o1 = outT + ((size_t)b * 512 + c1) * 4096;
#pragma unroll
    for (int m = 0; m < 8; m++) {
      const int r = 2 * m;
      const int rv = ((r & 2) << 1) | ((r & 4) >> 1) | ((r & 8) >> 3);
      const int i = t + (rv << 9);
      o0[i] = f2b(xr[r]); o1[i] = f2b(xi[r]);
    }
  }
}

// ---------------------------------------------------------------------------
extern "C" void kernel_launch(void* const* d_in, const int* in_sizes, int n_in,
                              void* d_out, int out_size, void* d_ws, size_t ws_size,
                              hipStream_t stream)
{
  const float* x   = (const float*)d_in[0];
  const float* Wu  = (const float*)d_in[1];
  const float* bu  = (const float*)d_in[2];
  const float* Wv  = (const float*)d_in[3];
  const float* bv  = (const float*)d_in[4];
  const float* Wo1 = (const float*)d_in[5];
  const float* bo1 = (const float*)d_in[6];
  const float* Wo2 = (const float*)d_in[7];
  const float* bo2 = (const float*)d_in[8];
  const float* dWp = (const float*)d_in[9];
  const float* dbp = (const float*)d_in[10];
  const float* dW1 = (const float*)d_in[11];
  const float* db1 = (const float*)d_in[12];
  const float* dW2 = (const float*)d_in[13];
  const float* db2 = (const float*)d_in[14];
  const float* dW3 = (const float*)d_in[15];
  const float* db3 = (const float*)d_in[16];
  float* out = (float*)d_out;

  char* wsb = (char*)d_ws;
  const size_t MB = 1u << 20;
  // bf16 weight pool @ 0-6 MB
  u16* WuT  = (u16*)wsb;                    // 1024x512
  u16* WvT  = WuT + 524288;                 // 512x512
  u16* Wo1T = WvT + 262144;                 // 1024x512
  u16* Wo2T = Wo1T + 524288;                // 512x1024
  u16* dW1T = Wo2T + 524288;                // 512x512
  u16* dW2T = dW1T + 262144;
  u16* dW3T = dW2T + 262144;
  // activations / scratch
  u16*    XNb   = (u16*)(wsb + 6 * MB);     // 32768x512 bf16 (dies after u/v)
  u16*    D0b   = (u16*)(wsb + 6 * MB);     // 8192x512 bf16 (over dead XNb)
  float*  D1    = (float*)(wsb + 14 * MB);  // 8192x512 fp32 (DPB hidden layers)
  float*  D1T   = (float*)(wsb + 14 * MB);  // 512x8192 fp32 (final DPB, transposed)
  u16*    CT    = (u16*)(wsb + 6 * MB);     // (8,512,4096) bf16 (after kfft)
  u16*    G     = (u16*)(wsb + 6 * MB);     // 32768x1024 bf16 (after transpose)
  u16*    VTb   = (u16*)(wsb + 38 * MB);    // (8,512,4096) bf16 (dies after conv)
  float2* ASPEC = (float2*)(wsb + 70 * MB); // 512x4097 c64 (~16.8MB)
  float2* TW    = (float2*)(wsb + 87 * MB); // 4096 c64
  u16*    CR    = (u16*)(wsb + 88 * MB);    // 32768x512 bf16
  u16*    U     = (u16*)(wsb + 128 * MB);   // 32768x1024 bf16

  dim3 wt_blk(32, 8);
  // weight transposes + casts
  wtrans_kernel<<<dim3(32, 16), wt_blk, 0, stream>>>(Wu, WuT, 512, 1024);
  wtrans_kernel<<<dim3(16, 16), wt_blk, 0, stream>>>(Wv, WvT, 512, 512);
  wtrans_kernel<<<dim3(32, 16), wt_blk, 0, stream>>>(Wo1, Wo1T, 512, 1024);
  wtrans_kernel<<<dim3(16, 32), wt_blk, 0, stream>>>(Wo2, Wo2T, 1024, 512);
  wtrans_kernel<<<dim3(16, 16), wt_blk, 0, stream>>>(dW1, dW1T, 512, 512);
  wtrans_kernel<<<dim3(16, 16), wt_blk, 0, stream>>>(dW2, dW2T, 512, 512);
  wtrans_kernel<<<dim3(16, 16), wt_blk, 0, stream>>>(dW3, dW3T, 512, 512);
  twiddle_init_kernel<<<8, 512, 0, stream>>>(TW);

  // pre-norm -> bf16
  srms_bf16_kernel<<<8192, 256, 0, stream>>>(x, XNb, 32768, 0);
  // v = silu(xn@Wv+bv) -> VTb channel-major bf16 (fused transpose)
  gemm128x256_bf16_kernel<2><<<dim3(2, 256), 512, 0, stream>>>(XNb, WvT, bv, nullptr, nullptr, VTb, 32768, 512, 512);
  // u = silu(xn@Wu+bu) -> U bf16
  gemm128x256_bf16_kernel<1><<<dim3(4, 256), 512, 0, stream>>>(XNb, WuT, bu, nullptr, nullptr, U, 32768, 1024, 512);

  // DPB MLP -> transposed circulant table D1T (512, 8192) fp32
  dpb0_kernel<<<2048, 256, 0, stream>>>(dWp, dbp, D0b);
  gemm_bf16_kernel<0><<<dim3(4, 64), 256, 0, stream>>>(D0b, dW1T, db1, nullptr, nullptr, D1, 8192, 512, 512);
  srms_bf16_kernel<<<2048, 256, 0, stream>>>(D1, D0b, 8192, 1);
  gemm_bf16_kernel<0><<<dim3(4, 64), 256, 0, stream>>>(D0b, dW2T, db2, nullptr, nullptr, D1, 8192, 512, 512);
  srms_bf16_kernel<<<2048, 256, 0, stream>>>(D1, D0b, 8192, 1);
  gemm_bf16_kernel<5><<<dim3(4, 64), 256, 0, stream>>>(D0b, dW3T, db3, nullptr, nullptr, D1T, 8192, 512, 512);
  // kernel spectra (coalesced rows of D1T), pre-scaled by 1/8192
  kfft_kernel<<<256, 512, 0, stream>>>(D1T, TW, ASPEC);
  // FFT conv: VTb -> CT (bf16, channel-major)
  conv_kernel<<<dim3(256, 8), 512, 0, stream>>>(VTb, ASPEC, TW, CT);
  // CT -> CR row-major bf16
  transpose_b16_kernel<<<dim3(128, 16, 8), wt_blk, 0, stream>>>(CT, CR);
  // gate: (CR@Wo1+bo1)*U -> G bf16
  gemm128x256_bf16_kernel<3><<<dim3(4, 256), 512, 0, stream>>>(CR, Wo1T, bo1, U, nullptr, G, 32768, 1024, 512);
  // final: G@Wo2 + bo2 + x -> out fp32
  gemm128x256_bf16_kernel<4><<<dim3(2, 256), 512, 0, stream>>>(G, Wo2T, bo2, nullptr, x, out, 32768, 512, 1024);
}